// Round 10
// baseline (157.502 us; speedup 1.0000x reference)
//
#include <hip/hip_runtime.h>
#include <hip/hip_bf16.h>

#define DIN 128
#define HC  128
#define NH  4

#define GB        256      // GEMM blocks in fused kernel
#define RANGES    8        // node ranges (LDS histogram partitions)
#define CHUNK_LOG 16       // edges per chunk = 65536
#define CNK       (1 << CHUNK_LOG)

typedef __attribute__((ext_vector_type(8))) short short8;
typedef __attribute__((ext_vector_type(4))) float floatx4;

__device__ inline short f2bf_bits(float f) {
    __hip_bfloat16 t = __float2bfloat16(f);
    return *reinterpret_cast<short*>(&t);
}
__device__ inline float bfbits2f(unsigned short u) {
    union { unsigned int i; float f; } c; c.i = ((unsigned int)u) << 16; return c.f;
}

// ---------------------------------------------------------------------------
// FUSED kernel, block-range split:
//   blocks [0, GB)   : h = bf16(x @ W + b) via MFMA + fused ali/alj logits
//   blocks [GB, ...) : LDS-partitioned edge histogram. Block (c,r) reads edge
//     chunk c (64K edges, L2-resident after first range touches it), counts
//     src in its node range via LDS atomics (no HBM write-through), stores
//     per-edge local rank and the (chunk,node) partial-count row cnt[c][i].
// ---------------------------------------------------------------------------
__global__ __launch_bounds__(256) void gemm_count(
    const float* __restrict__ x, const float* __restrict__ W,
    const float* __restrict__ b, const float* __restrict__ att,
    __hip_bfloat16* __restrict__ h, float* __restrict__ ali,
    float* __restrict__ alj,
    const int* __restrict__ src, unsigned short* __restrict__ cnt,
    unsigned short* __restrict__ rank16,
    int n, int ntiles, int E, int total, int rsize)
{
    __shared__ __align__(16) unsigned char smem[DIN * 136 * 2];  // 34816 B

    if (blockIdx.x >= GB) {
        // ---------------- LDS histogram part ----------------
        int* hist = (int*)smem;                       // rsize ints (25 KB)
        const int hb = blockIdx.x - GB;
        const int c = hb >> 3, r = hb & (RANGES - 1);
        const int base = r * rsize;
        const int sz = min(base + rsize, n) - base;
        for (int u = threadIdx.x; u < sz; u += 256) hist[u] = 0;
        __syncthreads();
        const int e0 = c << CHUNK_LOG;
        const int e1 = min(e0 + CNK, total);
        for (int e = e0 + threadIdx.x; e < e1; e += 256) {
            const int i = (e < E) ? src[e] : (e - E);
            const unsigned u = (unsigned)(i - base);
            if (u < (unsigned)sz)
                rank16[e] = (unsigned short)atomicAdd(&hist[u], 1);
        }
        __syncthreads();
        for (int u = threadIdx.x; u < sz; u += 256)
            cnt[(size_t)c * n + base + u] = (unsigned short)hist[u];
        return;
    }

    // ---------------- GEMM part ----------------
    auto Wt = reinterpret_cast<__hip_bfloat16(*)[136]>(smem);
    for (int idx = threadIdx.x; idx < DIN * HC; idx += 256) {
        const int k = idx >> 7, c = idx & 127;
        Wt[c][k] = __float2bfloat16(W[idx]);
    }
    __syncthreads();

    const int lane = threadIdx.x & 63;
    const int l15 = lane & 15, lg = lane >> 4;

    short8 bf[8][4];
    #pragma unroll
    for (int ct = 0; ct < 8; ++ct)
        #pragma unroll
        for (int ks = 0; ks < 4; ++ks)
            bf[ct][ks] = *(const short8*)(&Wt[ct * 16 + l15][ks * 32 + lg * 8]);

    float bc[8], ai_l[8], aj_l[8];
    #pragma unroll
    for (int ct = 0; ct < 8; ++ct) {
        bc[ct]   = b[ct * 16 + l15];
        ai_l[ct] = att[(ct >> 1) * 64 + (ct & 1) * 16 + l15];
        aj_l[ct] = att[(ct >> 1) * 64 + 32 + (ct & 1) * 16 + l15];
    }

    const int gw = (blockIdx.x * 256 + threadIdx.x) >> 6;
    const int nw = (GB * 256) >> 6;
    for (int tile = gw; tile < ntiles; tile += nw) {
        int row = tile * 16 + l15;
        if (row >= n) row = n - 1;              // safe duplicate load
        floatx4 acc[8];
        #pragma unroll
        for (int ct = 0; ct < 8; ++ct) acc[ct] = (floatx4)0.f;

        #pragma unroll
        for (int ks = 0; ks < 4; ++ks) {
            const float4 f0 = *(const float4*)(x + (size_t)row * DIN + ks * 32 + lg * 8);
            const float4 f1 = *(const float4*)(x + (size_t)row * DIN + ks * 32 + lg * 8 + 4);
            short8 af;
            af[0] = f2bf_bits(f0.x); af[1] = f2bf_bits(f0.y);
            af[2] = f2bf_bits(f0.z); af[3] = f2bf_bits(f0.w);
            af[4] = f2bf_bits(f1.x); af[5] = f2bf_bits(f1.y);
            af[6] = f2bf_bits(f1.z); af[7] = f2bf_bits(f1.w);
            #pragma unroll
            for (int ct = 0; ct < 8; ++ct)
                acc[ct] = __builtin_amdgcn_mfma_f32_16x16x32_bf16(
                    af, bf[ct][ks], acc[ct], 0, 0, 0);
        }

        #pragma unroll
        for (int reg = 0; reg < 4; ++reg) {
            const int r = tile * 16 + lg * 4 + reg;

            // h write (bf16)
            #pragma unroll
            for (int ct = 0; ct < 8; ++ct)
                if (r < n)
                    h[(size_t)r * HC + ct * 16 + l15] =
                        __float2bfloat16(acc[ct][reg] + bc[ct]);

            // fused logits: per-head dot over this row's 128 cols
            float pi[4], pj[4];
            #pragma unroll
            for (int hd = 0; hd < 4; ++hd) {
                float vi = 0.f, vj = 0.f;
                #pragma unroll
                for (int q = 0; q < 2; ++q) {
                    const int ct = hd * 2 + q;
                    const float hv = acc[ct][reg] + bc[ct];
                    vi = fmaf(hv, ai_l[ct], vi);
                    vj = fmaf(hv, aj_l[ct], vj);
                }
                #pragma unroll
                for (int m = 1; m <= 8; m <<= 1) {
                    vi += __shfl_xor(vi, m);
                    vj += __shfl_xor(vj, m);
                }
                pi[hd] = vi; pj[hd] = vj;
            }
            if (l15 < 8 && r < n) {
                const int hd = l15 & 3;
                float wi = pi[0];
                wi = (hd == 1) ? pi[1] : wi;
                wi = (hd == 2) ? pi[2] : wi;
                wi = (hd == 3) ? pi[3] : wi;
                float wj = pj[0];
                wj = (hd == 1) ? pj[1] : wj;
                wj = (hd == 2) ? pj[2] : wj;
                wj = (hd == 3) ? pj[3] : wj;
                if (l15 < 4) ali[(size_t)r * 4 + hd] = wi;
                else         alj[(size_t)r * 4 + hd] = wj;
            }
        }
    }
}

// ---------------------------------------------------------------------------
// scan1: per node i, (a) serial exclusive scan of cnt[c][i] over chunks
// (writes chunk-prefix back into cnt), producing deg; (b) intra-block
// exclusive scan of deg -> rowptr + per-block sums.
// ---------------------------------------------------------------------------
__global__ __launch_bounds__(256) void scan1(
    unsigned short* __restrict__ cnt, int* __restrict__ rowptr,
    int* __restrict__ bsum, int n, int nchunks)
{
    __shared__ int sh[256];
    const int t = threadIdx.x;
    const int i = blockIdx.x * 256 + t;
    int run = 0;
    if (i < n) {
        for (int c = 0; c < nchunks; ++c) {
            const size_t idx = (size_t)c * n + i;
            const int v = cnt[idx];
            cnt[idx] = (unsigned short)run;
            run += v;
        }
    }
    sh[t] = run;
    __syncthreads();
    #pragma unroll
    for (int off = 1; off < 256; off <<= 1) {
        const int u = (t >= off) ? sh[t - off] : 0;
        __syncthreads();
        sh[t] += u;
        __syncthreads();
    }
    if (i < n) rowptr[i] = sh[t] - run;      // exclusive within block
    if (t == 255) bsum[blockIdx.x] = sh[255];
}

// single block: exclusive scan of block sums -> boff
__global__ __launch_bounds__(1024) void scan2(
    const int* __restrict__ bsum, int* __restrict__ boff, int nb)
{
    __shared__ int sh[1024];
    const int t = threadIdx.x;
    const int v = (t < nb) ? bsum[t] : 0;
    sh[t] = v;
    __syncthreads();
    #pragma unroll
    for (int off = 1; off < 1024; off <<= 1) {
        const int u = (t >= off) ? sh[t - off] : 0;
        __syncthreads();
        sh[t] += u;
        __syncthreads();
    }
    if (t < nb) boff[t] = sh[t] - v;
}

// atomic-free scatter: pos = rowptr[i] + boff[i>>8] + cnt_prefix[c][i] + rank
__global__ __launch_bounds__(256) void scatter_edges(
    const int* __restrict__ src, const int* __restrict__ dst,
    const unsigned short* __restrict__ rank16,
    const unsigned short* __restrict__ cnt,
    const int* __restrict__ rowptr, const int* __restrict__ boff,
    unsigned short* __restrict__ csr, int E, int total, int n)
{
    const int e = blockIdx.x * 256 + threadIdx.x;
    if (e >= total) return;
    int i, j;
    if (e < E) { i = src[e]; j = dst[e]; }
    else       { i = e - E;  j = i; }
    const int pos = rowptr[i] + boff[i >> 8]
                  + (int)cnt[(size_t)(e >> CHUNK_LOG) * n + i]
                  + (int)rank16[e];
    csr[pos] = (unsigned short)j;
}

// ---------------------------------------------------------------------------
// One wave per node, single pass, unroll-8 over neighbors (8 independent
// h-row loads in flight). Lane owns 2 output cols of head hh = lane>>4;
// accumulates weighted sum + softmax denominator in identical serial order.
// Normalize + bias + ReLU fused into the single coalesced store.
// ---------------------------------------------------------------------------
__global__ __launch_bounds__(256) void aggregate_csr(
    const int* __restrict__ rowptr, const int* __restrict__ boff,
    const unsigned short* __restrict__ csr,
    const float* __restrict__ ali, const float* __restrict__ alj,
    const __hip_bfloat16* __restrict__ h, const float* __restrict__ bias,
    float* __restrict__ out, int n, int total)
{
    const int lane = threadIdx.x & 63;
    const int hh   = lane >> 4;
    const int gw = (blockIdx.x * 256 + threadIdx.x) >> 6;
    const int nw = (gridDim.x * 256) >> 6;
    const unsigned short* hu = (const unsigned short*)h;
    const float b0 = bias[lane * 2], b1 = bias[lane * 2 + 1];

    for (int i = gw; i < n; i += nw) {
        const int rs = rowptr[i] + boff[i >> 8];
        const int re = (i + 1 == n) ? total
                                    : rowptr[i + 1] + boff[(i + 1) >> 8];
        const float aii = ali[(size_t)i * 4 + hh];

        float acc0 = 0.f, acc1 = 0.f, s = 0.f;
        int t = rs;
        for (; t + 8 <= re; t += 8) {
            int jj[8]; float ll[8]; ushort2 uu[8];
            #pragma unroll
            for (int q = 0; q < 8; ++q) jj[q] = csr[t + q];
            #pragma unroll
            for (int q = 0; q < 8; ++q) ll[q] = alj[(size_t)jj[q] * 4 + hh];
            #pragma unroll
            for (int q = 0; q < 8; ++q)
                uu[q] = *(const ushort2*)(hu + (size_t)jj[q] * HC + lane * 2);
            #pragma unroll
            for (int q = 0; q < 8; ++q) {
                float l = aii + ll[q];
                l = l > 0.f ? l : 0.2f * l;
                const float ex = __expf(l);
                s += ex;
                acc0 = fmaf(ex, bfbits2f(uu[q].x), acc0);
                acc1 = fmaf(ex, bfbits2f(uu[q].y), acc1);
            }
        }
        for (; t + 4 <= re; t += 4) {
            int jj[4]; float ll[4]; ushort2 uu[4];
            #pragma unroll
            for (int q = 0; q < 4; ++q) jj[q] = csr[t + q];
            #pragma unroll
            for (int q = 0; q < 4; ++q) ll[q] = alj[(size_t)jj[q] * 4 + hh];
            #pragma unroll
            for (int q = 0; q < 4; ++q)
                uu[q] = *(const ushort2*)(hu + (size_t)jj[q] * HC + lane * 2);
            #pragma unroll
            for (int q = 0; q < 4; ++q) {
                float l = aii + ll[q];
                l = l > 0.f ? l : 0.2f * l;
                const float ex = __expf(l);
                s += ex;
                acc0 = fmaf(ex, bfbits2f(uu[q].x), acc0);
                acc1 = fmaf(ex, bfbits2f(uu[q].y), acc1);
            }
        }
        for (; t < re; ++t) {
            const int j = csr[t];
            float l = aii + alj[(size_t)j * 4 + hh];
            l = l > 0.f ? l : 0.2f * l;
            const float ex = __expf(l);
            s += ex;
            const ushort2 u = *(const ushort2*)(hu + (size_t)j * HC + lane * 2);
            acc0 = fmaf(ex, bfbits2f(u.x), acc0);
            acc1 = fmaf(ex, bfbits2f(u.y), acc1);
        }
        const float inv = 1.0f / s;
        float o0 = fmaf(acc0, inv, b0);
        float o1 = fmaf(acc1, inv, b1);
        float2 ov;
        ov.x = o0 > 0.f ? o0 : 0.f;
        ov.y = o1 > 0.f ? o1 : 0.f;
        *(float2*)(out + (size_t)i * HC + lane * 2) = ov;
    }
}

extern "C" void kernel_launch(void* const* d_in, const int* in_sizes, int n_in,
                              void* d_out, int out_size, void* d_ws, size_t ws_size,
                              hipStream_t stream)
{
    const float* x    = (const float*)d_in[0];
    const int*   ei   = (const int*)d_in[1];     // int32 (harness convention)
    const float* W    = (const float*)d_in[2];
    const float* b    = (const float*)d_in[3];
    const float* att  = (const float*)d_in[4];
    const float* bias = (const float*)d_in[5];

    const int n     = in_sizes[0] / DIN;   // 50000
    const int E     = in_sizes[1] / 2;     // 800000
    const int total = E + n;

    const int* src = ei;        // e_i (segment index)
    const int* dst = ei + E;    // e_j (gather index)

    const int nchunks = (total + CNK - 1) >> CHUNK_LOG;   // 13
    const int rsize   = (n + RANGES - 1) / RANGES;        // 6250
    const int nb      = (n + 255) / 256;                  // scan blocks (196)

    // workspace layout (~19.3 MB), 256B-aligned slices
    char* ws = (char*)d_ws;
    size_t off = 0;
    auto take = [&](size_t bytes) {
        char* p = ws + off;
        off += (bytes + 255) & ~(size_t)255;
        return p;
    };
    __hip_bfloat16* h   = (__hip_bfloat16*)take((size_t)n * HC * 2);
    float* ali    = (float*)take((size_t)n * NH * 4);
    float* alj    = (float*)take((size_t)n * NH * 4);
    int*   rowptr = (int*)take((size_t)(n + 1) * 4);
    int*   bsum   = (int*)take((size_t)nb * 4);
    int*   boff   = (int*)take((size_t)nb * 4);
    unsigned short* cnt    = (unsigned short*)take((size_t)nchunks * n * 2);
    unsigned short* rank16 = (unsigned short*)take((size_t)total * 2);
    unsigned short* csr    = (unsigned short*)take((size_t)total * 2);

    float* out = (float*)d_out;

    const int ntiles = (n + 15) / 16;
    gemm_count<<<GB + nchunks * RANGES, 256, 0, stream>>>(
        x, W, b, att, h, ali, alj, src, cnt, rank16,
        n, ntiles, E, total, rsize);

    scan1<<<nb, 256, 0, stream>>>(cnt, rowptr, bsum, n, nchunks);
    scan2<<<1, 1024, 0, stream>>>(bsum, boff, nb);

    const int eb = (total + 255) / 256;
    scatter_edges<<<eb, 256, 0, stream>>>(src, dst, rank16, cnt, rowptr, boff,
                                          csr, E, total, n);

    const int nodeBlocks = (n + 3) / 4;            // 4 waves/block, 1 node/wave
    aggregate_csr<<<nodeBlocks, 256, 0, stream>>>(rowptr, boff, csr, ali, alj,
                                                  h, bias, out, n, total);
}

// Round 11
// 135.633 us; speedup vs baseline: 1.1612x; 1.1612x over previous
//
#include <hip/hip_runtime.h>
#include <hip/hip_bf16.h>

#define DIN 128
#define HC  128
#define NH  4

#define CHUNK_LOG 15                 // 32768 edges per chunk
#define CNK       (1 << CHUNK_LOG)
#define SMEM_BYTES 100352            // >= ceil(50000/2)*4 hist, >= 34816 Wt

typedef __attribute__((ext_vector_type(8))) short short8;
typedef __attribute__((ext_vector_type(4))) float floatx4;

__device__ inline short f2bf_bits(float f) {
    __hip_bfloat16 t = __float2bfloat16(f);
    return *reinterpret_cast<short*>(&t);
}
__device__ inline float bfbits2f(unsigned short u) {
    union { unsigned int i; float f; } c; c.i = ((unsigned int)u) << 16; return c.f;
}

// ---------------------------------------------------------------------------
// FUSED kernel (grid = 256 blocks):
//   blocks [0, nchunks): first run a FULL-RANGE LDS histogram of one 32K-edge
//     chunk (50000 packed-ushort counters in 100KB LDS). All lanes active ->
//     rank16 writes fully coalesced; each chunk read once; cnt row coalesced.
//     Then fall through to the GEMM grid-stride loop (~3us late).
//   all blocks: h = bf16(x @ W + b) via MFMA + fused ali/alj logits.
// ---------------------------------------------------------------------------
__global__ __launch_bounds__(256) void gemm_count(
    const float* __restrict__ x, const float* __restrict__ W,
    const float* __restrict__ b, const float* __restrict__ att,
    __hip_bfloat16* __restrict__ h, float* __restrict__ ali,
    float* __restrict__ alj,
    const int* __restrict__ src, unsigned short* __restrict__ cnt,
    unsigned short* __restrict__ rank16,
    int n, int ntiles, int E, int total, int nchunks)
{
    __shared__ __align__(16) unsigned char smem[SMEM_BYTES];

    if (blockIdx.x < (unsigned)nchunks) {
        // ---------------- full-range LDS histogram of chunk c ----------------
        unsigned int* hist = (unsigned int*)smem;      // ceil(n/2) ints
        const int c = blockIdx.x;
        const int nInts = (n + 1) >> 1;
        for (int u = threadIdx.x; u < nInts; u += 256) hist[u] = 0u;
        __syncthreads();
        const int e0 = c << CHUNK_LOG;
        const int e1 = min(e0 + CNK, total);
        for (int e = e0 + threadIdx.x; e < e1; e += 256) {
            const int i = (e < E) ? src[e] : (e - E);
            const unsigned int sh  = (unsigned)(i & 1) * 16u;
            const unsigned int old = atomicAdd(&hist[i >> 1], 1u << sh);
            rank16[e] = (unsigned short)((old >> sh) & 0xffffu);
        }
        __syncthreads();
        unsigned short* row = cnt + (size_t)c * n;
        for (int u = threadIdx.x; u < n; u += 256)
            row[u] = (unsigned short)((hist[u >> 1] >> ((u & 1) * 16)) & 0xffffu);
        __syncthreads();   // done with hist LDS before Wt staging reuses it
    }

    // ---------------- GEMM part (all blocks) ----------------
    auto Wt = reinterpret_cast<__hip_bfloat16(*)[136]>(smem);
    for (int idx = threadIdx.x; idx < DIN * HC; idx += 256) {
        const int k = idx >> 7, c = idx & 127;
        Wt[c][k] = __float2bfloat16(W[idx]);
    }
    __syncthreads();

    const int lane = threadIdx.x & 63;
    const int l15 = lane & 15, lg = lane >> 4;

    short8 bf[8][4];
    #pragma unroll
    for (int ct = 0; ct < 8; ++ct)
        #pragma unroll
        for (int ks = 0; ks < 4; ++ks)
            bf[ct][ks] = *(const short8*)(&Wt[ct * 16 + l15][ks * 32 + lg * 8]);

    float bc[8], ai_l[8], aj_l[8];
    #pragma unroll
    for (int ct = 0; ct < 8; ++ct) {
        bc[ct]   = b[ct * 16 + l15];
        ai_l[ct] = att[(ct >> 1) * 64 + (ct & 1) * 16 + l15];
        aj_l[ct] = att[(ct >> 1) * 64 + 32 + (ct & 1) * 16 + l15];
    }

    const int gw = (blockIdx.x * 256 + threadIdx.x) >> 6;
    const int nw = (gridDim.x * 256) >> 6;
    for (int tile = gw; tile < ntiles; tile += nw) {
        int row = tile * 16 + l15;
        if (row >= n) row = n - 1;              // safe duplicate load
        floatx4 acc[8];
        #pragma unroll
        for (int ct = 0; ct < 8; ++ct) acc[ct] = (floatx4)0.f;

        #pragma unroll
        for (int ks = 0; ks < 4; ++ks) {
            const float4 f0 = *(const float4*)(x + (size_t)row * DIN + ks * 32 + lg * 8);
            const float4 f1 = *(const float4*)(x + (size_t)row * DIN + ks * 32 + lg * 8 + 4);
            short8 af;
            af[0] = f2bf_bits(f0.x); af[1] = f2bf_bits(f0.y);
            af[2] = f2bf_bits(f0.z); af[3] = f2bf_bits(f0.w);
            af[4] = f2bf_bits(f1.x); af[5] = f2bf_bits(f1.y);
            af[6] = f2bf_bits(f1.z); af[7] = f2bf_bits(f1.w);
            #pragma unroll
            for (int ct = 0; ct < 8; ++ct)
                acc[ct] = __builtin_amdgcn_mfma_f32_16x16x32_bf16(
                    af, bf[ct][ks], acc[ct], 0, 0, 0);
        }

        #pragma unroll
        for (int reg = 0; reg < 4; ++reg) {
            const int r = tile * 16 + lg * 4 + reg;

            // h write (bf16)
            #pragma unroll
            for (int ct = 0; ct < 8; ++ct)
                if (r < n)
                    h[(size_t)r * HC + ct * 16 + l15] =
                        __float2bfloat16(acc[ct][reg] + bc[ct]);

            // fused logits: per-head dot over this row's 128 cols
            float pi[4], pj[4];
            #pragma unroll
            for (int hd = 0; hd < 4; ++hd) {
                float vi = 0.f, vj = 0.f;
                #pragma unroll
                for (int q = 0; q < 2; ++q) {
                    const int ct = hd * 2 + q;
                    const float hv = acc[ct][reg] + bc[ct];
                    vi = fmaf(hv, ai_l[ct], vi);
                    vj = fmaf(hv, aj_l[ct], vj);
                }
                #pragma unroll
                for (int m = 1; m <= 8; m <<= 1) {
                    vi += __shfl_xor(vi, m);
                    vj += __shfl_xor(vj, m);
                }
                pi[hd] = vi; pj[hd] = vj;
            }
            if (l15 < 8 && r < n) {
                const int hd = l15 & 3;
                float wi = pi[0];
                wi = (hd == 1) ? pi[1] : wi;
                wi = (hd == 2) ? pi[2] : wi;
                wi = (hd == 3) ? pi[3] : wi;
                float wj = pj[0];
                wj = (hd == 1) ? pj[1] : wj;
                wj = (hd == 2) ? pj[2] : wj;
                wj = (hd == 3) ? pj[3] : wj;
                if (l15 < 4) ali[(size_t)r * 4 + hd] = wi;
                else         alj[(size_t)r * 4 + hd] = wj;
            }
        }
    }
}

// ---------------------------------------------------------------------------
// scan1: per node i, (a) serial exclusive scan of cnt[c][i] over chunks
// (writes chunk-prefix back into cnt), producing deg; (b) intra-block
// exclusive scan of deg -> rowptr + per-block sums.
// ---------------------------------------------------------------------------
__global__ __launch_bounds__(256) void scan1(
    unsigned short* __restrict__ cnt, int* __restrict__ rowptr,
    int* __restrict__ bsum, int n, int nchunks)
{
    __shared__ int sh[256];
    const int t = threadIdx.x;
    const int i = blockIdx.x * 256 + t;
    int run = 0;
    if (i < n) {
        for (int c = 0; c < nchunks; ++c) {
            const size_t idx = (size_t)c * n + i;
            const int v = cnt[idx];
            cnt[idx] = (unsigned short)run;
            run += v;
        }
    }
    sh[t] = run;
    __syncthreads();
    #pragma unroll
    for (int off = 1; off < 256; off <<= 1) {
        const int u = (t >= off) ? sh[t - off] : 0;
        __syncthreads();
        sh[t] += u;
        __syncthreads();
    }
    if (i < n) rowptr[i] = sh[t] - run;      // exclusive within block
    if (t == 255) bsum[blockIdx.x] = sh[255];
}

// single block: exclusive scan of block sums -> boff
__global__ __launch_bounds__(1024) void scan2(
    const int* __restrict__ bsum, int* __restrict__ boff, int nb)
{
    __shared__ int sh[1024];
    const int t = threadIdx.x;
    const int v = (t < nb) ? bsum[t] : 0;
    sh[t] = v;
    __syncthreads();
    #pragma unroll
    for (int off = 1; off < 1024; off <<= 1) {
        const int u = (t >= off) ? sh[t - off] : 0;
        __syncthreads();
        sh[t] += u;
        __syncthreads();
    }
    if (t < nb) boff[t] = sh[t] - v;
}

// atomic-free scatter: pos = rowptr[i] + boff[i>>8] + cnt_prefix[c][i] + rank
__global__ __launch_bounds__(256) void scatter_edges(
    const int* __restrict__ src, const int* __restrict__ dst,
    const unsigned short* __restrict__ rank16,
    const unsigned short* __restrict__ cnt,
    const int* __restrict__ rowptr, const int* __restrict__ boff,
    unsigned short* __restrict__ csr, int E, int total, int n)
{
    const int e = blockIdx.x * 256 + threadIdx.x;
    if (e >= total) return;
    int i, j;
    if (e < E) { i = src[e]; j = dst[e]; }
    else       { i = e - E;  j = i; }
    const int pos = rowptr[i] + boff[i >> 8]
                  + (int)cnt[(size_t)(e >> CHUNK_LOG) * n + i]
                  + (int)rank16[e];
    csr[pos] = (unsigned short)j;
}

// ---------------------------------------------------------------------------
// One wave per node, single pass, unroll-8 over neighbors (8 independent
// h-row loads in flight). Lane owns 2 output cols of head hh = lane>>4;
// accumulates weighted sum + softmax denominator in identical serial order.
// Normalize + bias + ReLU fused into the single coalesced store.
// ---------------------------------------------------------------------------
__global__ __launch_bounds__(256) void aggregate_csr(
    const int* __restrict__ rowptr, const int* __restrict__ boff,
    const unsigned short* __restrict__ csr,
    const float* __restrict__ ali, const float* __restrict__ alj,
    const __hip_bfloat16* __restrict__ h, const float* __restrict__ bias,
    float* __restrict__ out, int n, int total)
{
    const int lane = threadIdx.x & 63;
    const int hh   = lane >> 4;
    const int gw = (blockIdx.x * 256 + threadIdx.x) >> 6;
    const int nw = (gridDim.x * 256) >> 6;
    const unsigned short* hu = (const unsigned short*)h;
    const float b0 = bias[lane * 2], b1 = bias[lane * 2 + 1];

    for (int i = gw; i < n; i += nw) {
        const int rs = rowptr[i] + boff[i >> 8];
        const int re = (i + 1 == n) ? total
                                    : rowptr[i + 1] + boff[(i + 1) >> 8];
        const float aii = ali[(size_t)i * 4 + hh];

        float acc0 = 0.f, acc1 = 0.f, s = 0.f;
        int t = rs;
        for (; t + 8 <= re; t += 8) {
            int jj[8]; float ll[8]; ushort2 uu[8];
            #pragma unroll
            for (int q = 0; q < 8; ++q) jj[q] = csr[t + q];
            #pragma unroll
            for (int q = 0; q < 8; ++q) ll[q] = alj[(size_t)jj[q] * 4 + hh];
            #pragma unroll
            for (int q = 0; q < 8; ++q)
                uu[q] = *(const ushort2*)(hu + (size_t)jj[q] * HC + lane * 2);
            #pragma unroll
            for (int q = 0; q < 8; ++q) {
                float l = aii + ll[q];
                l = l > 0.f ? l : 0.2f * l;
                const float ex = __expf(l);
                s += ex;
                acc0 = fmaf(ex, bfbits2f(uu[q].x), acc0);
                acc1 = fmaf(ex, bfbits2f(uu[q].y), acc1);
            }
        }
        for (; t + 4 <= re; t += 4) {
            int jj[4]; float ll[4]; ushort2 uu[4];
            #pragma unroll
            for (int q = 0; q < 4; ++q) jj[q] = csr[t + q];
            #pragma unroll
            for (int q = 0; q < 4; ++q) ll[q] = alj[(size_t)jj[q] * 4 + hh];
            #pragma unroll
            for (int q = 0; q < 4; ++q)
                uu[q] = *(const ushort2*)(hu + (size_t)jj[q] * HC + lane * 2);
            #pragma unroll
            for (int q = 0; q < 4; ++q) {
                float l = aii + ll[q];
                l = l > 0.f ? l : 0.2f * l;
                const float ex = __expf(l);
                s += ex;
                acc0 = fmaf(ex, bfbits2f(uu[q].x), acc0);
                acc1 = fmaf(ex, bfbits2f(uu[q].y), acc1);
            }
        }
        for (; t < re; ++t) {
            const int j = csr[t];
            float l = aii + alj[(size_t)j * 4 + hh];
            l = l > 0.f ? l : 0.2f * l;
            const float ex = __expf(l);
            s += ex;
            const ushort2 u = *(const ushort2*)(hu + (size_t)j * HC + lane * 2);
            acc0 = fmaf(ex, bfbits2f(u.x), acc0);
            acc1 = fmaf(ex, bfbits2f(u.y), acc1);
        }
        const float inv = 1.0f / s;
        float o0 = fmaf(acc0, inv, b0);
        float o1 = fmaf(acc1, inv, b1);
        float2 ov;
        ov.x = o0 > 0.f ? o0 : 0.f;
        ov.y = o1 > 0.f ? o1 : 0.f;
        *(float2*)(out + (size_t)i * HC + lane * 2) = ov;
    }
}

extern "C" void kernel_launch(void* const* d_in, const int* in_sizes, int n_in,
                              void* d_out, int out_size, void* d_ws, size_t ws_size,
                              hipStream_t stream)
{
    const float* x    = (const float*)d_in[0];
    const int*   ei   = (const int*)d_in[1];     // int32 (harness convention)
    const float* W    = (const float*)d_in[2];
    const float* b    = (const float*)d_in[3];
    const float* att  = (const float*)d_in[4];
    const float* bias = (const float*)d_in[5];

    const int n     = in_sizes[0] / DIN;   // 50000
    const int E     = in_sizes[1] / 2;     // 800000
    const int total = E + n;

    const int* src = ei;        // e_i (segment index)
    const int* dst = ei + E;    // e_j (gather index)

    const int nchunks = (total + CNK - 1) >> CHUNK_LOG;   // 26
    const int nb      = (n + 255) / 256;                  // scan blocks (196)

    // workspace layout (~20 MB), 256B-aligned slices
    char* ws = (char*)d_ws;
    size_t off = 0;
    auto take = [&](size_t bytes) {
        char* p = ws + off;
        off += (bytes + 255) & ~(size_t)255;
        return p;
    };
    __hip_bfloat16* h   = (__hip_bfloat16*)take((size_t)n * HC * 2);
    float* ali    = (float*)take((size_t)n * NH * 4);
    float* alj    = (float*)take((size_t)n * NH * 4);
    int*   rowptr = (int*)take((size_t)(n + 1) * 4);
    int*   bsum   = (int*)take((size_t)nb * 4);
    int*   boff   = (int*)take((size_t)nb * 4);
    unsigned short* cnt    = (unsigned short*)take((size_t)nchunks * n * 2);
    unsigned short* rank16 = (unsigned short*)take((size_t)total * 2);
    unsigned short* csr    = (unsigned short*)take((size_t)total * 2);

    float* out = (float*)d_out;

    const int ntiles = (n + 15) / 16;
    gemm_count<<<256, 256, 0, stream>>>(x, W, b, att, h, ali, alj,
                                        src, cnt, rank16,
                                        n, ntiles, E, total, nchunks);

    scan1<<<nb, 256, 0, stream>>>(cnt, rowptr, bsum, n, nchunks);
    scan2<<<1, 1024, 0, stream>>>(bsum, boff, nb);

    const int eb = (total + 255) / 256;
    scatter_edges<<<eb, 256, 0, stream>>>(src, dst, rank16, cnt, rowptr, boff,
                                          csr, E, total, n);

    const int nodeBlocks = (n + 3) / 4;            // 4 waves/block, 1 node/wave
    aggregate_csr<<<nodeBlocks, 256, 0, stream>>>(rowptr, boff, csr, ali, alj,
                                                  h, bias, out, n, total);
}

// Round 12
// 129.896 us; speedup vs baseline: 1.2125x; 1.0442x over previous
//
#include <hip/hip_runtime.h>
#include <hip/hip_bf16.h>

#define DIN 128
#define HC  128
#define NH  4

#define CHUNK_LOG 15                 // 32768 edges per chunk
#define CNK       (1 << CHUNK_LOG)
#define HIST_BYTES 100352            // ceil(50000/2)*4 packed-ushort counters

#define GB 256                       // GEMM blocks in fused kernel
#define SB 512                       // scatter blocks in fused kernel

typedef __attribute__((ext_vector_type(8))) short short8;
typedef __attribute__((ext_vector_type(4))) float floatx4;

__device__ inline short f2bf_bits(float f) {
    __hip_bfloat16 t = __float2bfloat16(f);
    return *reinterpret_cast<short*>(&t);
}
__device__ inline float bfbits2f(unsigned short u) {
    union { unsigned int i; float f; } c; c.i = ((unsigned int)u) << 16; return c.f;
}

// ---------------------------------------------------------------------------
// Standalone full-range LDS histogram: one block per 32K-edge chunk, 50000
// packed-ushort counters in 100KB LDS. All lanes active; rank16 coalesced;
// each chunk read once; cnt row coalesced. Only 26 blocks -> 26 CUs, but
// total work is tiny (a few us). Keeping it standalone means the GEMM kernel
// is NOT saddled with 100KB static LDS (the R11 mistake: 1 block/CU).
// ---------------------------------------------------------------------------
__global__ __launch_bounds__(256) void hist(
    const int* __restrict__ src, unsigned short* __restrict__ cnt,
    unsigned short* __restrict__ rank16, int n, int E, int total)
{
    __shared__ unsigned int histo[HIST_BYTES / 4];
    const int c = blockIdx.x;
    const int nInts = (n + 1) >> 1;
    for (int u = threadIdx.x; u < nInts; u += 256) histo[u] = 0u;
    __syncthreads();
    const int e0 = c << CHUNK_LOG;
    const int e1 = min(e0 + CNK, total);
    for (int e = e0 + threadIdx.x; e < e1; e += 256) {
        const int i = (e < E) ? src[e] : (e - E);
        const unsigned int sh  = (unsigned)(i & 1) * 16u;
        const unsigned int old = atomicAdd(&histo[i >> 1], 1u << sh);
        rank16[e] = (unsigned short)((old >> sh) & 0xffffu);
    }
    __syncthreads();
    unsigned short* row = cnt + (size_t)c * n;
    for (int u = threadIdx.x; u < n; u += 256)
        row[u] = (unsigned short)((histo[u >> 1] >> ((u & 1) * 16)) & 0xffffu);
}

// ---------------------------------------------------------------------------
// scan1: per node i, (a) serial exclusive scan of cnt[c][i] over chunks
// (writes chunk-prefix back into cnt), producing deg; (b) intra-block
// exclusive scan of deg -> rowptr + per-block sums.
// ---------------------------------------------------------------------------
__global__ __launch_bounds__(256) void scan1(
    unsigned short* __restrict__ cnt, int* __restrict__ rowptr,
    int* __restrict__ bsum, int n, int nchunks)
{
    __shared__ int sh[256];
    const int t = threadIdx.x;
    const int i = blockIdx.x * 256 + t;
    int run = 0;
    if (i < n) {
        for (int c = 0; c < nchunks; ++c) {
            const size_t idx = (size_t)c * n + i;
            const int v = cnt[idx];
            cnt[idx] = (unsigned short)run;
            run += v;
        }
    }
    sh[t] = run;
    __syncthreads();
    #pragma unroll
    for (int off = 1; off < 256; off <<= 1) {
        const int u = (t >= off) ? sh[t - off] : 0;
        __syncthreads();
        sh[t] += u;
        __syncthreads();
    }
    if (i < n) rowptr[i] = sh[t] - run;      // exclusive within block
    if (t == 255) bsum[blockIdx.x] = sh[255];
}

// single block: exclusive scan of block sums -> boff
__global__ __launch_bounds__(1024) void scan2(
    const int* __restrict__ bsum, int* __restrict__ boff, int nb)
{
    __shared__ int sh[1024];
    const int t = threadIdx.x;
    const int v = (t < nb) ? bsum[t] : 0;
    sh[t] = v;
    __syncthreads();
    #pragma unroll
    for (int off = 1; off < 1024; off <<= 1) {
        const int u = (t >= off) ? sh[t - off] : 0;
        __syncthreads();
        sh[t] += u;
        __syncthreads();
    }
    if (t < nb) boff[t] = sh[t] - v;
}

// ---------------------------------------------------------------------------
// FUSED kernel, block-range split (both parts 35KB LDS -> 4 blocks/CU):
//   blocks [0, GB)       : h = bf16(x @ W + b) via MFMA + fused ali/alj logits
//   blocks [GB, GB+SB)   : atomic-free CSR scatter (random ushort writes ride
//                          under the GEMM's MFMA/LDS work)
// ---------------------------------------------------------------------------
__global__ __launch_bounds__(256) void gemm_scatter(
    const float* __restrict__ x, const float* __restrict__ W,
    const float* __restrict__ b, const float* __restrict__ att,
    __hip_bfloat16* __restrict__ h, float* __restrict__ ali,
    float* __restrict__ alj,
    const int* __restrict__ src, const int* __restrict__ dst,
    const unsigned short* __restrict__ rank16,
    const unsigned short* __restrict__ cnt,
    const int* __restrict__ rowptr, const int* __restrict__ boff,
    unsigned short* __restrict__ csr,
    int n, int ntiles, int E, int total)
{
    __shared__ __hip_bfloat16 Wt[DIN][136];

    if (blockIdx.x >= GB) {
        // ---------------- scatter part ----------------
        for (int e = (blockIdx.x - GB) * 256 + threadIdx.x; e < total;
             e += SB * 256) {
            int i, j;
            if (e < E) { i = src[e]; j = dst[e]; }
            else       { i = e - E;  j = i; }
            const int pos = rowptr[i] + boff[i >> 8]
                          + (int)cnt[(size_t)(e >> CHUNK_LOG) * n + i]
                          + (int)rank16[e];
            csr[pos] = (unsigned short)j;
        }
        return;
    }

    // ---------------- GEMM part ----------------
    for (int idx = threadIdx.x; idx < DIN * HC; idx += 256) {
        const int k = idx >> 7, c = idx & 127;
        Wt[c][k] = __float2bfloat16(W[idx]);
    }
    __syncthreads();

    const int lane = threadIdx.x & 63;
    const int l15 = lane & 15, lg = lane >> 4;

    short8 bf[8][4];
    #pragma unroll
    for (int ct = 0; ct < 8; ++ct)
        #pragma unroll
        for (int ks = 0; ks < 4; ++ks)
            bf[ct][ks] = *(const short8*)(&Wt[ct * 16 + l15][ks * 32 + lg * 8]);

    float bc[8], ai_l[8], aj_l[8];
    #pragma unroll
    for (int ct = 0; ct < 8; ++ct) {
        bc[ct]   = b[ct * 16 + l15];
        ai_l[ct] = att[(ct >> 1) * 64 + (ct & 1) * 16 + l15];
        aj_l[ct] = att[(ct >> 1) * 64 + 32 + (ct & 1) * 16 + l15];
    }

    const int gw = (blockIdx.x * 256 + threadIdx.x) >> 6;
    const int nw = (GB * 256) >> 6;
    for (int tile = gw; tile < ntiles; tile += nw) {
        int row = tile * 16 + l15;
        if (row >= n) row = n - 1;              // safe duplicate load
        floatx4 acc[8];
        #pragma unroll
        for (int ct = 0; ct < 8; ++ct) acc[ct] = (floatx4)0.f;

        #pragma unroll
        for (int ks = 0; ks < 4; ++ks) {
            const float4 f0 = *(const float4*)(x + (size_t)row * DIN + ks * 32 + lg * 8);
            const float4 f1 = *(const float4*)(x + (size_t)row * DIN + ks * 32 + lg * 8 + 4);
            short8 af;
            af[0] = f2bf_bits(f0.x); af[1] = f2bf_bits(f0.y);
            af[2] = f2bf_bits(f0.z); af[3] = f2bf_bits(f0.w);
            af[4] = f2bf_bits(f1.x); af[5] = f2bf_bits(f1.y);
            af[6] = f2bf_bits(f1.z); af[7] = f2bf_bits(f1.w);
            #pragma unroll
            for (int ct = 0; ct < 8; ++ct)
                acc[ct] = __builtin_amdgcn_mfma_f32_16x16x32_bf16(
                    af, bf[ct][ks], acc[ct], 0, 0, 0);
        }

        #pragma unroll
        for (int reg = 0; reg < 4; ++reg) {
            const int r = tile * 16 + lg * 4 + reg;

            // h write (bf16)
            #pragma unroll
            for (int ct = 0; ct < 8; ++ct)
                if (r < n)
                    h[(size_t)r * HC + ct * 16 + l15] =
                        __float2bfloat16(acc[ct][reg] + bc[ct]);

            // fused logits: per-head dot over this row's 128 cols
            float pi[4], pj[4];
            #pragma unroll
            for (int hd = 0; hd < 4; ++hd) {
                float vi = 0.f, vj = 0.f;
                #pragma unroll
                for (int q = 0; q < 2; ++q) {
                    const int ct = hd * 2 + q;
                    const float hv = acc[ct][reg] + bc[ct];
                    vi = fmaf(hv, ai_l[ct], vi);
                    vj = fmaf(hv, aj_l[ct], vj);
                }
                #pragma unroll
                for (int m = 1; m <= 8; m <<= 1) {
                    vi += __shfl_xor(vi, m);
                    vj += __shfl_xor(vj, m);
                }
                pi[hd] = vi; pj[hd] = vj;
            }
            if (l15 < 8 && r < n) {
                const int hd = l15 & 3;
                float wi = pi[0];
                wi = (hd == 1) ? pi[1] : wi;
                wi = (hd == 2) ? pi[2] : wi;
                wi = (hd == 3) ? pi[3] : wi;
                float wj = pj[0];
                wj = (hd == 1) ? pj[1] : wj;
                wj = (hd == 2) ? pj[2] : wj;
                wj = (hd == 3) ? pj[3] : wj;
                if (l15 < 4) ali[(size_t)r * 4 + hd] = wi;
                else         alj[(size_t)r * 4 + hd] = wj;
            }
        }
    }
}

// ---------------------------------------------------------------------------
// One wave per node, single pass, unroll-8 over neighbors (8 independent
// h-row loads in flight). Lane owns 2 output cols of head hh = lane>>4;
// accumulates weighted sum + softmax denominator in identical serial order.
// Normalize + bias + ReLU fused into the single coalesced store.
// ---------------------------------------------------------------------------
__global__ __launch_bounds__(256) void aggregate_csr(
    const int* __restrict__ rowptr, const int* __restrict__ boff,
    const unsigned short* __restrict__ csr,
    const float* __restrict__ ali, const float* __restrict__ alj,
    const __hip_bfloat16* __restrict__ h, const float* __restrict__ bias,
    float* __restrict__ out, int n, int total)
{
    const int lane = threadIdx.x & 63;
    const int hh   = lane >> 4;
    const int gw = (blockIdx.x * 256 + threadIdx.x) >> 6;
    const int nw = (gridDim.x * 256) >> 6;
    const unsigned short* hu = (const unsigned short*)h;
    const float b0 = bias[lane * 2], b1 = bias[lane * 2 + 1];

    for (int i = gw; i < n; i += nw) {
        const int rs = rowptr[i] + boff[i >> 8];
        const int re = (i + 1 == n) ? total
                                    : rowptr[i + 1] + boff[(i + 1) >> 8];
        const float aii = ali[(size_t)i * 4 + hh];

        float acc0 = 0.f, acc1 = 0.f, s = 0.f;
        int t = rs;
        for (; t + 8 <= re; t += 8) {
            int jj[8]; float ll[8]; ushort2 uu[8];
            #pragma unroll
            for (int q = 0; q < 8; ++q) jj[q] = csr[t + q];
            #pragma unroll
            for (int q = 0; q < 8; ++q) ll[q] = alj[(size_t)jj[q] * 4 + hh];
            #pragma unroll
            for (int q = 0; q < 8; ++q)
                uu[q] = *(const ushort2*)(hu + (size_t)jj[q] * HC + lane * 2);
            #pragma unroll
            for (int q = 0; q < 8; ++q) {
                float l = aii + ll[q];
                l = l > 0.f ? l : 0.2f * l;
                const float ex = __expf(l);
                s += ex;
                acc0 = fmaf(ex, bfbits2f(uu[q].x), acc0);
                acc1 = fmaf(ex, bfbits2f(uu[q].y), acc1);
            }
        }
        for (; t + 4 <= re; t += 4) {
            int jj[4]; float ll[4]; ushort2 uu[4];
            #pragma unroll
            for (int q = 0; q < 4; ++q) jj[q] = csr[t + q];
            #pragma unroll
            for (int q = 0; q < 4; ++q) ll[q] = alj[(size_t)jj[q] * 4 + hh];
            #pragma unroll
            for (int q = 0; q < 4; ++q)
                uu[q] = *(const ushort2*)(hu + (size_t)jj[q] * HC + lane * 2);
            #pragma unroll
            for (int q = 0; q < 4; ++q) {
                float l = aii + ll[q];
                l = l > 0.f ? l : 0.2f * l;
                const float ex = __expf(l);
                s += ex;
                acc0 = fmaf(ex, bfbits2f(uu[q].x), acc0);
                acc1 = fmaf(ex, bfbits2f(uu[q].y), acc1);
            }
        }
        for (; t < re; ++t) {
            const int j = csr[t];
            float l = aii + alj[(size_t)j * 4 + hh];
            l = l > 0.f ? l : 0.2f * l;
            const float ex = __expf(l);
            s += ex;
            const ushort2 u = *(const ushort2*)(hu + (size_t)j * HC + lane * 2);
            acc0 = fmaf(ex, bfbits2f(u.x), acc0);
            acc1 = fmaf(ex, bfbits2f(u.y), acc1);
        }
        const float inv = 1.0f / s;
        float o0 = fmaf(acc0, inv, b0);
        float o1 = fmaf(acc1, inv, b1);
        float2 ov;
        ov.x = o0 > 0.f ? o0 : 0.f;
        ov.y = o1 > 0.f ? o1 : 0.f;
        *(float2*)(out + (size_t)i * HC + lane * 2) = ov;
    }
}

extern "C" void kernel_launch(void* const* d_in, const int* in_sizes, int n_in,
                              void* d_out, int out_size, void* d_ws, size_t ws_size,
                              hipStream_t stream)
{
    const float* x    = (const float*)d_in[0];
    const int*   ei   = (const int*)d_in[1];     // int32 (harness convention)
    const float* W    = (const float*)d_in[2];
    const float* b    = (const float*)d_in[3];
    const float* att  = (const float*)d_in[4];
    const float* bias = (const float*)d_in[5];

    const int n     = in_sizes[0] / DIN;   // 50000
    const int E     = in_sizes[1] / 2;     // 800000
    const int total = E + n;

    const int* src = ei;        // e_i (segment index)
    const int* dst = ei + E;    // e_j (gather index)

    const int nchunks = (total + CNK - 1) >> CHUNK_LOG;   // 26
    const int nb      = (n + 255) / 256;                  // scan blocks (196)

    // workspace layout (~20 MB), 256B-aligned slices
    char* ws = (char*)d_ws;
    size_t off = 0;
    auto take = [&](size_t bytes) {
        char* p = ws + off;
        off += (bytes + 255) & ~(size_t)255;
        return p;
    };
    __hip_bfloat16* h   = (__hip_bfloat16*)take((size_t)n * HC * 2);
    float* ali    = (float*)take((size_t)n * NH * 4);
    float* alj    = (float*)take((size_t)n * NH * 4);
    int*   rowptr = (int*)take((size_t)(n + 1) * 4);
    int*   bsum   = (int*)take((size_t)nb * 4);
    int*   boff   = (int*)take((size_t)nb * 4);
    unsigned short* cnt    = (unsigned short*)take((size_t)nchunks * n * 2);
    unsigned short* rank16 = (unsigned short*)take((size_t)total * 2);
    unsigned short* csr    = (unsigned short*)take((size_t)total * 2);

    float* out = (float*)d_out;

    hist<<<nchunks, 256, 0, stream>>>(src, cnt, rank16, n, E, total);
    scan1<<<nb, 256, 0, stream>>>(cnt, rowptr, bsum, n, nchunks);
    scan2<<<1, 1024, 0, stream>>>(bsum, boff, nb);

    const int ntiles = (n + 15) / 16;
    gemm_scatter<<<GB + SB, 256, 0, stream>>>(
        x, W, b, att, h, ali, alj,
        src, dst, rank16, cnt, rowptr, boff, csr,
        n, ntiles, E, total);

    const int nodeBlocks = (n + 3) / 4;            // 4 waves/block, 1 node/wave
    aggregate_csr<<<nodeBlocks, 256, 0, stream>>>(rowptr, boff, csr, ali, alj,
                                                  h, bias, out, n, total);
}

// Round 13
// 94.419 us; speedup vs baseline: 1.6681x; 1.3757x over previous
//
#include <hip/hip_runtime.h>
#include <hip/hip_bf16.h>

#define DIN 128
#define HC  128
#define NH  4

#define CHUNK_LOG 15                 // 32768 edges per chunk
#define CNK       (1 << CHUNK_LOG)
#define HIST_BYTES 100352            // ceil(50000/2)*4 packed-ushort counters

#define GB 256                       // GEMM blocks in fused kernel
#define SB 512                       // scatter blocks in fused kernel

typedef __attribute__((ext_vector_type(8))) short short8;
typedef __attribute__((ext_vector_type(4))) float floatx4;

__device__ inline short f2bf_bits(float f) {
    __hip_bfloat16 t = __float2bfloat16(f);
    return *reinterpret_cast<short*>(&t);
}
__device__ inline float bfbits2f(unsigned short u) {
    union { unsigned int i; float f; } c; c.i = ((unsigned int)u) << 16; return c.f;
}

// ---------------------------------------------------------------------------
// Full-range LDS histogram, one block per 32K-edge chunk. 1024 threads
// (16 waves/CU despite the 100KB LDS -> 1 block/CU) + 4-deep ILP batching:
// the R12 version at 256 threads was a 68us latency chain (4 waves, 128
// dependent load->atomic rounds); this is 8 rounds with 16 waves.
// ---------------------------------------------------------------------------
__global__ __launch_bounds__(1024) void hist(
    const int* __restrict__ src, unsigned short* __restrict__ cnt,
    unsigned short* __restrict__ rank16, int n, int E, int total)
{
    __shared__ unsigned int histo[HIST_BYTES / 4];
    const int c = blockIdx.x;
    const int nInts = (n + 1) >> 1;
    for (int u = threadIdx.x; u < nInts; u += 1024) histo[u] = 0u;
    __syncthreads();

    const int e0 = c << CHUNK_LOG;
    const int e1 = min(e0 + CNK, total);
    for (int base = e0; base < e1; base += 4096) {
        int ii[4], ee[4];
        #pragma unroll
        for (int q = 0; q < 4; ++q) {
            const int e = base + q * 1024 + (int)threadIdx.x;
            ee[q] = e;
            ii[q] = (e < e1) ? ((e < E) ? src[e] : (e - E)) : -1;
        }
        #pragma unroll
        for (int q = 0; q < 4; ++q) {
            if (ii[q] >= 0) {
                const unsigned int sh  = (unsigned)(ii[q] & 1) * 16u;
                const unsigned int old = atomicAdd(&histo[ii[q] >> 1], 1u << sh);
                rank16[ee[q]] = (unsigned short)((old >> sh) & 0xffffu);
            }
        }
    }
    __syncthreads();
    unsigned short* row = cnt + (size_t)c * n;
    for (int u = threadIdx.x; u < n; u += 1024)
        row[u] = (unsigned short)((histo[u >> 1] >> ((u & 1) * 16)) & 0xffffu);
}

// ---------------------------------------------------------------------------
// scan1: per node i, (a) serial exclusive scan of cnt[c][i] over chunks
// (writes chunk-prefix back into cnt), producing deg; (b) intra-block
// exclusive scan of deg -> rowptr + per-block sums.
// ---------------------------------------------------------------------------
__global__ __launch_bounds__(256) void scan1(
    unsigned short* __restrict__ cnt, int* __restrict__ rowptr,
    int* __restrict__ bsum, int n, int nchunks)
{
    __shared__ int sh[256];
    const int t = threadIdx.x;
    const int i = blockIdx.x * 256 + t;
    int run = 0;
    if (i < n) {
        for (int c = 0; c < nchunks; ++c) {
            const size_t idx = (size_t)c * n + i;
            const int v = cnt[idx];
            cnt[idx] = (unsigned short)run;
            run += v;
        }
    }
    sh[t] = run;
    __syncthreads();
    #pragma unroll
    for (int off = 1; off < 256; off <<= 1) {
        const int u = (t >= off) ? sh[t - off] : 0;
        __syncthreads();
        sh[t] += u;
        __syncthreads();
    }
    if (i < n) rowptr[i] = sh[t] - run;      // exclusive within block
    if (t == 255) bsum[blockIdx.x] = sh[255];
}

// single block: exclusive scan of block sums -> boff
__global__ __launch_bounds__(1024) void scan2(
    const int* __restrict__ bsum, int* __restrict__ boff, int nb)
{
    __shared__ int sh[1024];
    const int t = threadIdx.x;
    const int v = (t < nb) ? bsum[t] : 0;
    sh[t] = v;
    __syncthreads();
    #pragma unroll
    for (int off = 1; off < 1024; off <<= 1) {
        const int u = (t >= off) ? sh[t - off] : 0;
        __syncthreads();
        sh[t] += u;
        __syncthreads();
    }
    if (t < nb) boff[t] = sh[t] - v;
}

// ---------------------------------------------------------------------------
// FUSED kernel, block-range split (35KB LDS -> 4 blocks/CU):
//   blocks [0, GB)       : h = bf16(x @ W + b) via MFMA + fused ali/alj logits
//   blocks [GB, GB+SB)   : atomic-free CSR scatter (random ushort writes ride
//                          under the GEMM's MFMA/LDS work)
// ---------------------------------------------------------------------------
__global__ __launch_bounds__(256) void gemm_scatter(
    const float* __restrict__ x, const float* __restrict__ W,
    const float* __restrict__ b, const float* __restrict__ att,
    __hip_bfloat16* __restrict__ h, float* __restrict__ ali,
    float* __restrict__ alj,
    const int* __restrict__ src, const int* __restrict__ dst,
    const unsigned short* __restrict__ rank16,
    const unsigned short* __restrict__ cnt,
    const int* __restrict__ rowptr, const int* __restrict__ boff,
    unsigned short* __restrict__ csr,
    int n, int ntiles, int E, int total)
{
    __shared__ __hip_bfloat16 Wt[DIN][136];

    if (blockIdx.x >= GB) {
        // ---------------- scatter part ----------------
        for (int e = (blockIdx.x - GB) * 256 + threadIdx.x; e < total;
             e += SB * 256) {
            int i, j;
            if (e < E) { i = src[e]; j = dst[e]; }
            else       { i = e - E;  j = i; }
            const int pos = rowptr[i] + boff[i >> 8]
                          + (int)cnt[(size_t)(e >> CHUNK_LOG) * n + i]
                          + (int)rank16[e];
            csr[pos] = (unsigned short)j;
        }
        return;
    }

    // ---------------- GEMM part ----------------
    for (int idx = threadIdx.x; idx < DIN * HC; idx += 256) {
        const int k = idx >> 7, c = idx & 127;
        Wt[c][k] = __float2bfloat16(W[idx]);
    }
    __syncthreads();

    const int lane = threadIdx.x & 63;
    const int l15 = lane & 15, lg = lane >> 4;

    short8 bf[8][4];
    #pragma unroll
    for (int ct = 0; ct < 8; ++ct)
        #pragma unroll
        for (int ks = 0; ks < 4; ++ks)
            bf[ct][ks] = *(const short8*)(&Wt[ct * 16 + l15][ks * 32 + lg * 8]);

    float bc[8], ai_l[8], aj_l[8];
    #pragma unroll
    for (int ct = 0; ct < 8; ++ct) {
        bc[ct]   = b[ct * 16 + l15];
        ai_l[ct] = att[(ct >> 1) * 64 + (ct & 1) * 16 + l15];
        aj_l[ct] = att[(ct >> 1) * 64 + 32 + (ct & 1) * 16 + l15];
    }

    const int gw = (blockIdx.x * 256 + threadIdx.x) >> 6;
    const int nw = (GB * 256) >> 6;
    for (int tile = gw; tile < ntiles; tile += nw) {
        int row = tile * 16 + l15;
        if (row >= n) row = n - 1;              // safe duplicate load
        floatx4 acc[8];
        #pragma unroll
        for (int ct = 0; ct < 8; ++ct) acc[ct] = (floatx4)0.f;

        #pragma unroll
        for (int ks = 0; ks < 4; ++ks) {
            const float4 f0 = *(const float4*)(x + (size_t)row * DIN + ks * 32 + lg * 8);
            const float4 f1 = *(const float4*)(x + (size_t)row * DIN + ks * 32 + lg * 8 + 4);
            short8 af;
            af[0] = f2bf_bits(f0.x); af[1] = f2bf_bits(f0.y);
            af[2] = f2bf_bits(f0.z); af[3] = f2bf_bits(f0.w);
            af[4] = f2bf_bits(f1.x); af[5] = f2bf_bits(f1.y);
            af[6] = f2bf_bits(f1.z); af[7] = f2bf_bits(f1.w);
            #pragma unroll
            for (int ct = 0; ct < 8; ++ct)
                acc[ct] = __builtin_amdgcn_mfma_f32_16x16x32_bf16(
                    af, bf[ct][ks], acc[ct], 0, 0, 0);
        }

        #pragma unroll
        for (int reg = 0; reg < 4; ++reg) {
            const int r = tile * 16 + lg * 4 + reg;

            // h write (bf16)
            #pragma unroll
            for (int ct = 0; ct < 8; ++ct)
                if (r < n)
                    h[(size_t)r * HC + ct * 16 + l15] =
                        __float2bfloat16(acc[ct][reg] + bc[ct]);

            // fused logits: per-head dot over this row's 128 cols
            float pi[4], pj[4];
            #pragma unroll
            for (int hd = 0; hd < 4; ++hd) {
                float vi = 0.f, vj = 0.f;
                #pragma unroll
                for (int q = 0; q < 2; ++q) {
                    const int ct = hd * 2 + q;
                    const float hv = acc[ct][reg] + bc[ct];
                    vi = fmaf(hv, ai_l[ct], vi);
                    vj = fmaf(hv, aj_l[ct], vj);
                }
                #pragma unroll
                for (int m = 1; m <= 8; m <<= 1) {
                    vi += __shfl_xor(vi, m);
                    vj += __shfl_xor(vj, m);
                }
                pi[hd] = vi; pj[hd] = vj;
            }
            if (l15 < 8 && r < n) {
                const int hd = l15 & 3;
                float wi = pi[0];
                wi = (hd == 1) ? pi[1] : wi;
                wi = (hd == 2) ? pi[2] : wi;
                wi = (hd == 3) ? pi[3] : wi;
                float wj = pj[0];
                wj = (hd == 1) ? pj[1] : wj;
                wj = (hd == 2) ? pj[2] : wj;
                wj = (hd == 3) ? pj[3] : wj;
                if (l15 < 4) ali[(size_t)r * 4 + hd] = wi;
                else         alj[(size_t)r * 4 + hd] = wj;
            }
        }
    }
}

// ---------------------------------------------------------------------------
// One wave per node, single pass, unroll-8 over neighbors (8 independent
// h-row loads in flight). Lane owns 2 output cols of head hh = lane>>4;
// accumulates weighted sum + softmax denominator in identical serial order.
// Normalize + bias + ReLU fused into the single coalesced store.
// ---------------------------------------------------------------------------
__global__ __launch_bounds__(256) void aggregate_csr(
    const int* __restrict__ rowptr, const int* __restrict__ boff,
    const unsigned short* __restrict__ csr,
    const float* __restrict__ ali, const float* __restrict__ alj,
    const __hip_bfloat16* __restrict__ h, const float* __restrict__ bias,
    float* __restrict__ out, int n, int total)
{
    const int lane = threadIdx.x & 63;
    const int hh   = lane >> 4;
    const int gw = (blockIdx.x * 256 + threadIdx.x) >> 6;
    const int nw = (gridDim.x * 256) >> 6;
    const unsigned short* hu = (const unsigned short*)h;
    const float b0 = bias[lane * 2], b1 = bias[lane * 2 + 1];

    for (int i = gw; i < n; i += nw) {
        const int rs = rowptr[i] + boff[i >> 8];
        const int re = (i + 1 == n) ? total
                                    : rowptr[i + 1] + boff[(i + 1) >> 8];
        const float aii = ali[(size_t)i * 4 + hh];

        float acc0 = 0.f, acc1 = 0.f, s = 0.f;
        int t = rs;
        for (; t + 8 <= re; t += 8) {
            int jj[8]; float ll[8]; ushort2 uu[8];
            #pragma unroll
            for (int q = 0; q < 8; ++q) jj[q] = csr[t + q];
            #pragma unroll
            for (int q = 0; q < 8; ++q) ll[q] = alj[(size_t)jj[q] * 4 + hh];
            #pragma unroll
            for (int q = 0; q < 8; ++q)
                uu[q] = *(const ushort2*)(hu + (size_t)jj[q] * HC + lane * 2);
            #pragma unroll
            for (int q = 0; q < 8; ++q) {
                float l = aii + ll[q];
                l = l > 0.f ? l : 0.2f * l;
                const float ex = __expf(l);
                s += ex;
                acc0 = fmaf(ex, bfbits2f(uu[q].x), acc0);
                acc1 = fmaf(ex, bfbits2f(uu[q].y), acc1);
            }
        }
        for (; t + 4 <= re; t += 4) {
            int jj[4]; float ll[4]; ushort2 uu[4];
            #pragma unroll
            for (int q = 0; q < 4; ++q) jj[q] = csr[t + q];
            #pragma unroll
            for (int q = 0; q < 4; ++q) ll[q] = alj[(size_t)jj[q] * 4 + hh];
            #pragma unroll
            for (int q = 0; q < 4; ++q)
                uu[q] = *(const ushort2*)(hu + (size_t)jj[q] * HC + lane * 2);
            #pragma unroll
            for (int q = 0; q < 4; ++q) {
                float l = aii + ll[q];
                l = l > 0.f ? l : 0.2f * l;
                const float ex = __expf(l);
                s += ex;
                acc0 = fmaf(ex, bfbits2f(uu[q].x), acc0);
                acc1 = fmaf(ex, bfbits2f(uu[q].y), acc1);
            }
        }
        for (; t < re; ++t) {
            const int j = csr[t];
            float l = aii + alj[(size_t)j * 4 + hh];
            l = l > 0.f ? l : 0.2f * l;
            const float ex = __expf(l);
            s += ex;
            const ushort2 u = *(const ushort2*)(hu + (size_t)j * HC + lane * 2);
            acc0 = fmaf(ex, bfbits2f(u.x), acc0);
            acc1 = fmaf(ex, bfbits2f(u.y), acc1);
        }
        const float inv = 1.0f / s;
        float o0 = fmaf(acc0, inv, b0);
        float o1 = fmaf(acc1, inv, b1);
        float2 ov;
        ov.x = o0 > 0.f ? o0 : 0.f;
        ov.y = o1 > 0.f ? o1 : 0.f;
        *(float2*)(out + (size_t)i * HC + lane * 2) = ov;
    }
}

extern "C" void kernel_launch(void* const* d_in, const int* in_sizes, int n_in,
                              void* d_out, int out_size, void* d_ws, size_t ws_size,
                              hipStream_t stream)
{
    const float* x    = (const float*)d_in[0];
    const int*   ei   = (const int*)d_in[1];     // int32 (harness convention)
    const float* W    = (const float*)d_in[2];
    const float* b    = (const float*)d_in[3];
    const float* att  = (const float*)d_in[4];
    const float* bias = (const float*)d_in[5];

    const int n     = in_sizes[0] / DIN;   // 50000
    const int E     = in_sizes[1] / 2;     // 800000
    const int total = E + n;

    const int* src = ei;        // e_i (segment index)
    const int* dst = ei + E;    // e_j (gather index)

    const int nchunks = (total + CNK - 1) >> CHUNK_LOG;   // 26
    const int nb      = (n + 255) / 256;                  // scan blocks (196)

    // workspace layout (~20 MB), 256B-aligned slices
    char* ws = (char*)d_ws;
    size_t off = 0;
    auto take = [&](size_t bytes) {
        char* p = ws + off;
        off += (bytes + 255) & ~(size_t)255;
        return p;
    };
    __hip_bfloat16* h   = (__hip_bfloat16*)take((size_t)n * HC * 2);
    float* ali    = (float*)take((size_t)n * NH * 4);
    float* alj    = (float*)take((size_t)n * NH * 4);
    int*   rowptr = (int*)take((size_t)(n + 1) * 4);
    int*   bsum   = (int*)take((size_t)nb * 4);
    int*   boff   = (int*)take((size_t)nb * 4);
    unsigned short* cnt    = (unsigned short*)take((size_t)nchunks * n * 2);
    unsigned short* rank16 = (unsigned short*)take((size_t)total * 2);
    unsigned short* csr    = (unsigned short*)take((size_t)total * 2);

    float* out = (float*)d_out;

    hist<<<nchunks, 1024, 0, stream>>>(src, cnt, rank16, n, E, total);
    scan1<<<nb, 256, 0, stream>>>(cnt, rowptr, bsum, n, nchunks);
    scan2<<<1, 1024, 0, stream>>>(bsum, boff, nb);

    const int ntiles = (n + 15) / 16;
    gemm_scatter<<<GB + SB, 256, 0, stream>>>(
        x, W, b, att, h, ali, alj,
        src, dst, rank16, cnt, rowptr, boff, csr,
        n, ntiles, E, total);

    const int nodeBlocks = (n + 3) / 4;            // 4 waves/block, 1 node/wave
    aggregate_csr<<<nodeBlocks, 256, 0, stream>>>(rowptr, boff, csr, ali, alj,
                                                  h, bias, out, n, total);
}